// Round 15
// baseline (2342.604 us; speedup 1.0000x reference)
//
#include <hip/hip_runtime.h>

#define D_ 1024
#define H_ 16
#define DK_ 64
#define S_ 1024
#define B_ 4

typedef __attribute__((ext_vector_type(4))) float f32x4;
typedef __attribute__((ext_vector_type(8))) short bf16x8;
typedef __attribute__((ext_vector_type(4))) unsigned int u32x4;

__device__ __forceinline__ unsigned short f2bf(float f) {
  unsigned u = __builtin_bit_cast(unsigned, f);
  u += 0x7FFFu + ((u >> 16) & 1u);
  return (unsigned short)(u >> 16);
}

__device__ __forceinline__ float bf2f(unsigned short s) {
  return __builtin_bit_cast(float, (unsigned)s << 16);
}

__device__ __forceinline__ bf16x8 ldg8(const unsigned short* p) {
  return __builtin_bit_cast(bf16x8, *reinterpret_cast<const u32x4*>(p));
}

__device__ __forceinline__ f32x4 mfma16(bf16x8 a, bf16x8 b, f32x4 c) {
  return __builtin_amdgcn_mfma_f32_16x16x32_bf16(a, b, c, 0, 0, 0);
}

// ---------------- fp32 -> bf16 conversion (weights only) ----------------
struct CvtJobs {
  const float* src[4];
  unsigned short* dst[4];
};

__global__ void k_convert(CvtJobs jobs) {
  const int j = blockIdx.y;
  const float* __restrict__ s = jobs.src[j];
  unsigned short* __restrict__ d = jobs.dst[j];
  const int n4 = 262144;
  const int stride = gridDim.x * blockDim.x;
  for (int i = blockIdx.x * blockDim.x + threadIdx.x; i < n4; i += stride) {
    float4 v = reinterpret_cast<const float4*>(s)[i];
    unsigned long long pk =
        (unsigned long long)f2bf(v.x) |
        ((unsigned long long)f2bf(v.y) << 16) |
        ((unsigned long long)f2bf(v.z) << 32) |
        ((unsigned long long)f2bf(v.w) << 48);
    reinterpret_cast<unsigned long long*>(d)[i] = pk;
  }
}

// ---------------- generic NT GEMM body: C[m,n] = (sum_k A[m,k]*B[n,k] + bias[n])*scale
// M=N=K=1024, BM=128 BN=64 BK=32. bid in [0,512), XCD-chunked (bz|m|n).
// mode 0: ->qh/kh bf16 [B,H,S,DK]; mode 1: ->vT bf16 [B,H,DK,S]; mode 2: -> d_out fp32.
// AF32: A fp32 (converted in staging). SUM2: A = Ap+Ap2 (bf16 partials).
template <int AF32, int SUM2>
__device__ __forceinline__ void gemm_body(
    int bid, int mode,
    const void* __restrict__ Ap, const void* __restrict__ Ap2, int lda, long azs,
    const unsigned short* __restrict__ Bp,
    const float* __restrict__ bias,
    void* __restrict__ Cp, float scale)
{
  __shared__ unsigned short As[128 * 40];
  __shared__ unsigned short Bs[64 * 40];
  const int tid = threadIdx.x;
  const int lane = tid & 63;
  const int w = tid >> 6;
  const int wm = (w >> 1) * 64;      // 2 wave-rows of 64
  const int wn = (w & 1) * 32;       // 2 wave-cols of 32
  const int L = ((bid & 7) << 6) | (bid >> 3);   // XCD-chunked, bijective
  const int n0 = (L & 15) * 64;
  const int m0 = ((L >> 4) & 7) * 128;
  const int bz = L >> 7;
  const int srow = tid >> 1;         // A staging: 128 rows, 2 halves
  const int shalf = tid & 1;
  const int brow = tid >> 2;         // B staging: 64 rows, 4 chunks of 8
  const int bq = tid & 3;
  const int l15 = lane & 15;
  const int lg = lane >> 4;

  f32x4 acc[4][2] = {};

  for (int kt = 0; kt < 32; ++kt) {
    const long aoff = (long)bz * azs + (long)(m0 + srow) * lda + kt * 32 + shalf * 16;
    if (AF32) {
      const float4* g4 = reinterpret_cast<const float4*>((const float*)Ap + aoff);
      unsigned* dst = reinterpret_cast<unsigned*>(&As[srow * 40 + shalf * 16]);
      #pragma unroll
      for (int i = 0; i < 4; ++i) {
        float4 v = g4[i];
        dst[2 * i]     = (unsigned)f2bf(v.x) | ((unsigned)f2bf(v.y) << 16);
        dst[2 * i + 1] = (unsigned)f2bf(v.z) | ((unsigned)f2bf(v.w) << 16);
      }
    } else if (SUM2) {
      const unsigned short* ga = (const unsigned short*)Ap + aoff;
      const unsigned short* ga2 = (const unsigned short*)Ap2 + aoff;
      u32x4 va[2] = { *reinterpret_cast<const u32x4*>(ga), *reinterpret_cast<const u32x4*>(ga + 8) };
      u32x4 vb[2] = { *reinterpret_cast<const u32x4*>(ga2), *reinterpret_cast<const u32x4*>(ga2 + 8) };
      unsigned* dst = reinterpret_cast<unsigned*>(&As[srow * 40 + shalf * 16]);
      #pragma unroll
      for (int p = 0; p < 2; ++p)
        #pragma unroll
        for (int i = 0; i < 4; ++i) {
          const unsigned x = va[p][i], y = vb[p][i];
          const float lo = __builtin_bit_cast(float, x << 16) + __builtin_bit_cast(float, y << 16);
          const float hi = __builtin_bit_cast(float, x & 0xffff0000u) + __builtin_bit_cast(float, y & 0xffff0000u);
          dst[p * 4 + i] = (unsigned)f2bf(lo) | ((unsigned)f2bf(hi) << 16);
        }
    } else {
      const unsigned short* ga = (const unsigned short*)Ap + aoff;
      u32x4 av0 = *reinterpret_cast<const u32x4*>(ga);
      u32x4 av1 = *reinterpret_cast<const u32x4*>(ga + 8);
      *reinterpret_cast<u32x4*>(&As[srow * 40 + shalf * 16]) = av0;
      *reinterpret_cast<u32x4*>(&As[srow * 40 + shalf * 16 + 8]) = av1;
    }
    {
      const unsigned short* gb = Bp + (long)(n0 + brow) * 1024 + kt * 32 + bq * 8;
      *reinterpret_cast<u32x4*>(&Bs[brow * 40 + bq * 8]) = *reinterpret_cast<const u32x4*>(gb);
    }
    __syncthreads();
    bf16x8 af[4], bfr[2];
    #pragma unroll
    for (int i = 0; i < 4; ++i)
      af[i] = __builtin_bit_cast(bf16x8, *reinterpret_cast<const u32x4*>(&As[(wm + i * 16 + l15) * 40 + lg * 8]));
    #pragma unroll
    for (int i = 0; i < 2; ++i)
      bfr[i] = __builtin_bit_cast(bf16x8, *reinterpret_cast<const u32x4*>(&Bs[(wn + i * 16 + l15) * 40 + lg * 8]));
    #pragma unroll
    for (int mf = 0; mf < 4; ++mf)
      #pragma unroll
      for (int nf = 0; nf < 2; ++nf)
        acc[mf][nf] = mfma16(af[mf], bfr[nf], acc[mf][nf]);
    __syncthreads();
  }

  #pragma unroll
  for (int nf = 0; nf < 2; ++nf) {
    const int gc = n0 + wn + nf * 16 + l15;
    const float bv = bias[gc];
    #pragma unroll
    for (int mf = 0; mf < 4; ++mf) {
      #pragma unroll
      for (int r = 0; r < 4; ++r) {
        const int gr = m0 + wm + mf * 16 + lg * 4 + r;
        float v = (acc[mf][nf][r] + bv) * scale;
        if (mode == 0) {
          ((unsigned short*)Cp)[(((long)bz * H_ + (gc >> 6)) * S_ + gr) * DK_ + (gc & 63)] = f2bf(v);
        } else if (mode == 1) {
          ((unsigned short*)Cp)[(((long)bz * H_ + (gc >> 6)) * DK_ + (gc & 63)) * S_ + gr] = f2bf(v);
        } else {
          ((float*)Cp)[(long)gr * (B_ * D_) + (long)bz * D_ + gc] = v;
        }
      }
    }
  }
}

// fat projection launch: 3 independent GEMMs in one dispatch (grid 1536)
struct ProjArgs {
  const float* X[3];
  const unsigned short* W[3];
  const float* bias[3];
  void* out[3];
  float scale[3];
  int mode[3];
};

__global__ __launch_bounds__(256) void k_proj3(ProjArgs pa) {
  const int which = blockIdx.x >> 9;
  const int inner = blockIdx.x & 511;
  gemm_body<1, 0>(inner, pa.mode[which], pa.X[which], nullptr, 4096, 1024L,
                  pa.W[which], pa.bias[which], pa.out[which], pa.scale[which]);
}

// O-projection: A = sum of two bf16 partial slabs
__global__ __launch_bounds__(256) void k_gemm_o(
    const unsigned short* __restrict__ Ap, const unsigned short* __restrict__ Ap2,
    const unsigned short* __restrict__ Bp, const float* __restrict__ bias,
    float* __restrict__ Cp) {
  gemm_body<0, 1>(blockIdx.x, 2, Ap, Ap2, 1024, 1048576L, Bp, bias, Cp, 1.0f);
}

// ---------------- softmax stats: m, 1/l per (b,h,q). Barrier-free streaming.
// grid 512 x 256 thr = 2048 waves (8 waves/CU); wave = (bh, 32 q-rows).
__global__ __launch_bounds__(256, 4) void k_stats(
    const unsigned short* __restrict__ qh,
    const unsigned short* __restrict__ kh,
    float2* __restrict__ mlout)
{
  const int tid = threadIdx.x;
  const int lane = tid & 63;
  const int w = tid >> 6;
  const int l15 = lane & 15;
  const int lg = lane >> 4;
  const int L = ((blockIdx.x & 7) << 6) | (blockIdx.x >> 3);  // XCD-chunked
  const int wtask = L * 4 + w;
  const int qq = wtask & 31;
  const int bh = wtask >> 5;
  const int q0 = qq * 32;

  bf16x8 qf[2][2];
  #pragma unroll
  for (int t = 0; t < 2; ++t) {
    const long qoff = ((long)bh * S_ + q0 + t * 16 + l15) * DK_ + lg * 8;
    qf[t][0] = ldg8(qh + qoff);
    qf[t][1] = ldg8(qh + qoff + 32);
  }
  const unsigned short* kbase = kh + (long)bh * S_ * DK_;

  float m[2], l[2];
  #pragma unroll
  for (int t = 0; t < 2; ++t) { m[t] = -3.0e38f; l[t] = 0.0f; }

  for (int kt = 0; kt < 16; ++kt) {
    bf16x8 kf[4][2];
    #pragma unroll
    for (int nf = 0; nf < 4; ++nf) {
      const unsigned short* kp = kbase + (long)(kt * 64 + nf * 16 + l15) * DK_ + lg * 8;
      kf[nf][0] = ldg8(kp);
      kf[nf][1] = ldg8(kp + 32);
    }
    #pragma unroll
    for (int t = 0; t < 2; ++t) {
      f32x4 sa[4] = {};
      #pragma unroll
      for (int nf = 0; nf < 4; ++nf) {
        sa[nf] = mfma16(kf[nf][0], qf[t][0], sa[nf]);   // swapped: lane owns q = l15
        sa[nf] = mfma16(kf[nf][1], qf[t][1], sa[nf]);
      }
      float tm = -3.0e38f;
      #pragma unroll
      for (int nf = 0; nf < 4; ++nf)
        #pragma unroll
        for (int r = 0; r < 4; ++r) tm = fmaxf(tm, sa[nf][r]);
      tm = fmaxf(tm, __shfl_xor(tm, 16));
      tm = fmaxf(tm, __shfl_xor(tm, 32));
      const float mn = fmaxf(m[t], tm);
      float ps = 0.0f;
      #pragma unroll
      for (int nf = 0; nf < 4; ++nf)
        #pragma unroll
        for (int r = 0; r < 4; ++r) ps += __expf(sa[nf][r] - mn);
      ps += __shfl_xor(ps, 16);
      ps += __shfl_xor(ps, 32);
      l[t] = l[t] * __expf(m[t] - mn) + ps;
      m[t] = mn;
    }
  }
  if (lane < 16) {
    #pragma unroll
    for (int t = 0; t < 2; ++t)
      mlout[(long)bh * S_ + q0 + t * 16 + l15] = make_float2(m[t], 1.0f / l[t]);
  }
}

// ---------------- fused pass2 v2: 512-thread blocks (8 waves), wave handles 2 heads
// {w, w+8}; IN-PLACE p->attn2 single 32KB buffer (R14 unified layout; same-address
// read/write per thread, hazard-free with 3 barriers); 4 blocks/CU target.
// Grid (64 qt, 2 half, 4 b). R14 swizzle/layout formulas throughout.
__global__ __launch_bounds__(512, 8) void k_attn2(
    const unsigned short* __restrict__ qh,
    const unsigned short* __restrict__ kh,
    const unsigned short* __restrict__ vT,
    const float2* __restrict__ mlin,
    const float* __restrict__ head_att,
    const float* __restrict__ ln_g,
    const float* __restrict__ ln_b,
    unsigned short* __restrict__ Ym0,
    float* __restrict__ att_out)
{
  __shared__ unsigned short pS[16 * 1024];   // plane h/g: [q16][kc64] bf16, XOR-swizzled; in-place
  __shared__ float haS[256];
  __shared__ float lngS[16];
  __shared__ float lnbS[16];
  const int tid = threadIdx.x;
  const int lane = tid & 63;
  const int w = tid >> 6;        // 0..7
  const int l15 = lane & 15;
  const int lg = lane >> 4;
  const int b = blockIdx.z;
  const int half = blockIdx.y;
  const int q0 = blockIdx.x * 16;
  const int kt0 = half * 8;

  if (tid < 256) haS[tid] = head_att[tid];
  if (tid < 16) { lngS[tid] = ln_g[tid]; lnbS[tid] = ln_b[tid]; }

  const int bh0 = b * H_ + w;
  const int bh1 = bh0 + 8;
  const long qo0 = ((long)bh0 * S_ + q0 + l15) * DK_ + lg * 8;
  const long qo1 = ((long)bh1 * S_ + q0 + l15) * DK_ + lg * 8;
  bf16x8 qf0a = ldg8(qh + qo0), qf0b = ldg8(qh + qo0 + 32);
  bf16x8 qf1a = ldg8(qh + qo1), qf1b = ldg8(qh + qo1 + 32);
  const unsigned short* kb0 = kh + (long)bh0 * S_ * DK_;
  const unsigned short* kb1 = kh + (long)bh1 * S_ * DK_;
  const unsigned short* vb0 = vT + (long)bh0 * DK_ * S_;
  const unsigned short* vb1 = vT + (long)bh1 * DK_ * S_;
  const float2 ml0 = mlin[(long)bh0 * S_ + q0 + l15];
  const float2 ml1 = mlin[(long)bh1 * S_ + q0 + l15];

  unsigned short* Ym = Ym0 + (long)half * (B_ * S_ * D_);
  char* pc = reinterpret_cast<char*>(pS);
  f32x4 yacc0[4] = {};
  f32x4 yacc1[4] = {};

  for (int kt = kt0; kt < kt0 + 8; ++kt) {
    // QK^T for both heads (swapped): lane q=l15, kc = nf*16+lg*4+r
    #pragma unroll
    for (int hh = 0; hh < 2; ++hh) {
      const unsigned short* kb = hh ? kb1 : kb0;
      const bf16x8 qa = hh ? qf1a : qf0a;
      const bf16x8 qb = hh ? qf1b : qf0b;
      const float2 ml = hh ? ml1 : ml0;
      f32x4 sa[4] = {};
      #pragma unroll
      for (int nf = 0; nf < 4; ++nf) {
        const unsigned short* kp = kb + (long)(kt * 64 + nf * 16 + l15) * DK_ + lg * 8;
        sa[nf] = mfma16(ldg8(kp), qa, sa[nf]);
        sa[nf] = mfma16(ldg8(kp + 32), qb, sa[nf]);
      }
      const int plane = w + 8 * hh;
      #pragma unroll
      for (int nf = 0; nf < 4; ++nf) {
        const unsigned e0 = f2bf(__expf(sa[nf][0] - ml.x) * ml.y);
        const unsigned e1 = f2bf(__expf(sa[nf][1] - ml.x) * ml.y);
        const unsigned e2 = f2bf(__expf(sa[nf][2] - ml.x) * ml.y);
        const unsigned e3 = f2bf(__expf(sa[nf][3] - ml.x) * ml.y);
        const unsigned long long pk =
            (unsigned long long)(e0 | (e1 << 16)) |
            ((unsigned long long)(e2 | (e3 << 16)) << 32);
        unsigned bo = (unsigned)(plane * 2048 + l15 * 128 + (nf * 16 + lg * 4) * 2);
        bo ^= (unsigned)((l15 & 7) << 4);
        *reinterpret_cast<unsigned long long*>(pc + bo) = pk;
      }
    }
    __syncthreads();   // B1: p ready

    // mix + LN, in place; thread owns q in {2w, 2w+1}, kc = lane
    #pragma unroll
    for (int qq = 0; qq < 2; ++qq) {
      const int q = w * 2 + qq;
      const unsigned mixoff = (unsigned)((q * 128 + lane * 2) ^ ((q & 7) << 4));
      float mx[16];
      #pragma unroll
      for (int g = 0; g < 16; ++g) mx[g] = 0.0f;
      #pragma unroll
      for (int h = 0; h < 16; ++h) {
        const float p = bf2f(*reinterpret_cast<const unsigned short*>(pc + h * 2048 + mixoff));
        #pragma unroll
        for (int g4 = 0; g4 < 4; ++g4) {
          const float4 hv = reinterpret_cast<const float4*>(&haS[h * 16])[g4];
          mx[g4 * 4 + 0] += p * hv.x;
          mx[g4 * 4 + 1] += p * hv.y;
          mx[g4 * 4 + 2] += p * hv.z;
          mx[g4 * 4 + 3] += p * hv.w;
        }
      }
      float mean = 0.0f;
      #pragma unroll
      for (int g = 0; g < 16; ++g) mean += mx[g];
      mean *= 0.0625f;
      float var = 0.0f;
      #pragma unroll
      for (int g = 0; g < 16; ++g) { const float dd = mx[g] - mean; var += dd * dd; }
      var *= 0.0625f;
      const float rs = rsqrtf(var + 1e-5f);

      float am = 0.0f;
      #pragma unroll
      for (int g = 0; g < 16; ++g) {
        const float o = (mx[g] - mean) * rs * lngS[g] + lnbS[g];
        am += o;
        *reinterpret_cast<unsigned short*>(pc + g * 2048 + mixoff) = f2bf(o);
      }
      att_out[(long)b * S_ * S_ + (long)(q0 + q) * S_ + kt * 64 + lane] = am * 0.0625f;
    }
    __syncthreads();   // B2: attn2 ready

    // PV for both heads: A = attn2 plane (swizzled b128), B = vT rows (global)
    #pragma unroll
    for (int hh = 0; hh < 2; ++hh) {
      const int plane = w + 8 * hh;
      const unsigned short* vb = hh ? vb1 : vb0;
      f32x4* yacc = hh ? yacc1 : yacc0;
      bf16x8 pa0, pa1;
      {
        const unsigned ub = (unsigned)(plane * 2048 + l15 * 128 + lg * 16);
        const unsigned swz = (unsigned)((l15 & 7) << 4);
        pa0 = __builtin_bit_cast(bf16x8, *reinterpret_cast<const u32x4*>(pc + (ub ^ swz)));
        pa1 = __builtin_bit_cast(bf16x8, *reinterpret_cast<const u32x4*>(pc + ((ub + 64) ^ swz)));
      }
      #pragma unroll
      for (int nf = 0; nf < 4; ++nf) {
        const unsigned short* vp = vb + (long)(nf * 16 + l15) * S_ + kt * 64 + lg * 8;
        yacc[nf] = mfma16(pa0, ldg8(vp), yacc[nf]);
        yacc[nf] = mfma16(pa1, ldg8(vp + 32), yacc[nf]);
      }
    }
    __syncthreads();   // B3: PV reads done before next iter's p-writes
  }

  // epilogue: partial merged-head Y (bf16) [B,S,D] for this kc-half, both heads
  #pragma unroll
  for (int hh = 0; hh < 2; ++hh) {
    const int head = w + 8 * hh;
    const f32x4* yacc = hh ? yacc1 : yacc0;
    #pragma unroll
    for (int nf = 0; nf < 4; ++nf)
      #pragma unroll
      for (int r = 0; r < 4; ++r)
        Ym[((long)b * S_ + q0 + lg * 4 + r) * D_ + head * 64 + nf * 16 + l15] = f2bf(yacc[nf][r]);
  }
}

extern "C" void kernel_launch(void* const* d_in, const int* in_sizes, int n_in,
                              void* d_out, int out_size, void* d_ws, size_t ws_size,
                              hipStream_t stream) {
  const float* q_in = (const float*)d_in[0];
  const float* k_in = (const float*)d_in[1];
  const float* v_in = (const float*)d_in[2];
  const float* Wq = (const float*)d_in[3];
  const float* bq = (const float*)d_in[4];
  const float* Wk = (const float*)d_in[5];
  const float* bk = (const float*)d_in[6];
  const float* Wv = (const float*)d_in[7];
  const float* bv = (const float*)d_in[8];
  const float* Wo = (const float*)d_in[9];
  const float* bo = (const float*)d_in[10];
  const float* head_att = (const float*)d_in[11];
  const float* ln_g = (const float*)d_in[12];
  const float* ln_b = (const float*)d_in[13];

  char* ws = (char*)d_ws;
  const long MB = 1048576L;
  unsigned short* Wqb = (unsigned short*)(ws);
  unsigned short* Wkb = (unsigned short*)(ws + 2 * MB);
  unsigned short* Wvb = (unsigned short*)(ws + 4 * MB);
  unsigned short* Wob = (unsigned short*)(ws + 6 * MB);
  unsigned short* qhp = (unsigned short*)(ws + 8 * MB);
  unsigned short* khp = (unsigned short*)(ws + 16 * MB);
  unsigned short* vTp = (unsigned short*)(ws + 24 * MB);
  unsigned short* Ymb = (unsigned short*)(ws + 32 * MB);   // 2 x 8 MB bf16 partials
  float2* mlb = (float2*)(ws + 48 * MB);                   // 512 KB

  CvtJobs cj;
  cj.src[0] = Wq; cj.dst[0] = Wqb;
  cj.src[1] = Wk; cj.dst[1] = Wkb;
  cj.src[2] = Wv; cj.dst[2] = Wvb;
  cj.src[3] = Wo; cj.dst[3] = Wob;
  k_convert<<<dim3(256, 4), 256, 0, stream>>>(cj);

  // fat launch: q (pre-scaled by 1/8), k, v projections in one dispatch
  ProjArgs pa;
  pa.X[0] = q_in; pa.W[0] = Wqb; pa.bias[0] = bq; pa.out[0] = qhp; pa.scale[0] = 0.125f; pa.mode[0] = 0;
  pa.X[1] = k_in; pa.W[1] = Wkb; pa.bias[1] = bk; pa.out[1] = khp; pa.scale[1] = 1.0f;   pa.mode[1] = 0;
  pa.X[2] = v_in; pa.W[2] = Wvb; pa.bias[2] = bv; pa.out[2] = vTp; pa.scale[2] = 1.0f;   pa.mode[2] = 1;
  k_proj3<<<1536, 256, 0, stream>>>(pa);

  k_stats<<<512, 256, 0, stream>>>(qhp, khp, mlb);

  float* att_map = (float*)d_out + (long)S_ * B_ * D_;
  k_attn2<<<dim3(64, 2, 4), 512, 0, stream>>>(qhp, khp, vTp, mlb, head_att, ln_g, ln_b,
                                              Ymb, att_map);

  k_gemm_o<<<512, 256, 0, stream>>>(Ymb, Ymb + (long)B_ * S_ * D_, Wob, bo, (float*)d_out);
}

// Round 16
// 287.598 us; speedup vs baseline: 8.1454x; 8.1454x over previous
//
#include <hip/hip_runtime.h>

#define D_ 1024
#define H_ 16
#define DK_ 64
#define S_ 1024
#define B_ 4

typedef __attribute__((ext_vector_type(4))) float f32x4;
typedef __attribute__((ext_vector_type(8))) short bf16x8;
typedef __attribute__((ext_vector_type(4))) unsigned int u32x4;

__device__ __forceinline__ unsigned short f2bf(float f) {
  unsigned u = __builtin_bit_cast(unsigned, f);
  u += 0x7FFFu + ((u >> 16) & 1u);
  return (unsigned short)(u >> 16);
}

__device__ __forceinline__ float bf2f(unsigned short s) {
  return __builtin_bit_cast(float, (unsigned)s << 16);
}

__device__ __forceinline__ bf16x8 ldg8(const unsigned short* p) {
  return __builtin_bit_cast(bf16x8, *reinterpret_cast<const u32x4*>(p));
}

__device__ __forceinline__ f32x4 mfma16(bf16x8 a, bf16x8 b, f32x4 c) {
  return __builtin_amdgcn_mfma_f32_16x16x32_bf16(a, b, c, 0, 0, 0);
}

// ---------------- generic NT GEMM body: C[m,n] = (sum_k A[m,k]*B[n,k] + bias[n])*scale
// M=N=K=1024, BM=128 BN=64 BK=32. bid in [0,512), XCD-chunked (bz|m|n).
// B operand is fp32 (weights), converted to bf16 during LDS staging (k_convert fused).
// mode 0: ->qh/kh bf16 [B,H,S,DK]; mode 1: ->vT bf16 [B,H,DK,S]; mode 2: -> d_out fp32.
// AF32: A fp32 (converted in staging). SUM2: A = Ap+Ap2 (bf16 partials).
template <int AF32, int SUM2>
__device__ __forceinline__ void gemm_body(
    int bid, int mode,
    const void* __restrict__ Ap, const void* __restrict__ Ap2, int lda, long azs,
    const float* __restrict__ Bp,
    const float* __restrict__ bias,
    void* __restrict__ Cp, float scale)
{
  __shared__ unsigned short As[128 * 40];
  __shared__ unsigned short Bs[64 * 40];
  const int tid = threadIdx.x;
  const int lane = tid & 63;
  const int w = tid >> 6;
  const int wm = (w >> 1) * 64;      // 2 wave-rows of 64
  const int wn = (w & 1) * 32;       // 2 wave-cols of 32
  const int L = ((bid & 7) << 6) | (bid >> 3);   // XCD-chunked, bijective
  const int n0 = (L & 15) * 64;
  const int m0 = ((L >> 4) & 7) * 128;
  const int bz = L >> 7;
  const int srow = tid >> 1;         // A staging: 128 rows, 2 halves
  const int shalf = tid & 1;
  const int brow = tid >> 2;         // B staging: 64 rows, 4 chunks of 8
  const int bq = tid & 3;
  const int l15 = lane & 15;
  const int lg = lane >> 4;

  f32x4 acc[4][2] = {};

  for (int kt = 0; kt < 32; ++kt) {
    const long aoff = (long)bz * azs + (long)(m0 + srow) * lda + kt * 32 + shalf * 16;
    if (AF32) {
      const float4* g4 = reinterpret_cast<const float4*>((const float*)Ap + aoff);
      unsigned* dst = reinterpret_cast<unsigned*>(&As[srow * 40 + shalf * 16]);
      #pragma unroll
      for (int i = 0; i < 4; ++i) {
        float4 v = g4[i];
        dst[2 * i]     = (unsigned)f2bf(v.x) | ((unsigned)f2bf(v.y) << 16);
        dst[2 * i + 1] = (unsigned)f2bf(v.z) | ((unsigned)f2bf(v.w) << 16);
      }
    } else if (SUM2) {
      const unsigned short* ga = (const unsigned short*)Ap + aoff;
      const unsigned short* ga2 = (const unsigned short*)Ap2 + aoff;
      u32x4 va[2] = { *reinterpret_cast<const u32x4*>(ga), *reinterpret_cast<const u32x4*>(ga + 8) };
      u32x4 vb[2] = { *reinterpret_cast<const u32x4*>(ga2), *reinterpret_cast<const u32x4*>(ga2 + 8) };
      unsigned* dst = reinterpret_cast<unsigned*>(&As[srow * 40 + shalf * 16]);
      #pragma unroll
      for (int p = 0; p < 2; ++p)
        #pragma unroll
        for (int i = 0; i < 4; ++i) {
          const unsigned x = va[p][i], y = vb[p][i];
          const float lo = __builtin_bit_cast(float, x << 16) + __builtin_bit_cast(float, y << 16);
          const float hi = __builtin_bit_cast(float, x & 0xffff0000u) + __builtin_bit_cast(float, y & 0xffff0000u);
          dst[p * 4 + i] = (unsigned)f2bf(lo) | ((unsigned)f2bf(hi) << 16);
        }
    } else {
      const unsigned short* ga = (const unsigned short*)Ap + aoff;
      u32x4 av0 = *reinterpret_cast<const u32x4*>(ga);
      u32x4 av1 = *reinterpret_cast<const u32x4*>(ga + 8);
      *reinterpret_cast<u32x4*>(&As[srow * 40 + shalf * 16]) = av0;
      *reinterpret_cast<u32x4*>(&As[srow * 40 + shalf * 16 + 8]) = av1;
    }
    {
      // B staging: fp32 weights -> bf16 (conversion fused; same f2bf rounding as k_convert)
      const float4* gb = reinterpret_cast<const float4*>(Bp + (long)(n0 + brow) * 1024 + kt * 32 + bq * 8);
      float4 v0 = gb[0];
      float4 v1 = gb[1];
      unsigned* dst = reinterpret_cast<unsigned*>(&Bs[brow * 40 + bq * 8]);
      dst[0] = (unsigned)f2bf(v0.x) | ((unsigned)f2bf(v0.y) << 16);
      dst[1] = (unsigned)f2bf(v0.z) | ((unsigned)f2bf(v0.w) << 16);
      dst[2] = (unsigned)f2bf(v1.x) | ((unsigned)f2bf(v1.y) << 16);
      dst[3] = (unsigned)f2bf(v1.z) | ((unsigned)f2bf(v1.w) << 16);
    }
    __syncthreads();
    bf16x8 af[4], bfr[2];
    #pragma unroll
    for (int i = 0; i < 4; ++i)
      af[i] = __builtin_bit_cast(bf16x8, *reinterpret_cast<const u32x4*>(&As[(wm + i * 16 + l15) * 40 + lg * 8]));
    #pragma unroll
    for (int i = 0; i < 2; ++i)
      bfr[i] = __builtin_bit_cast(bf16x8, *reinterpret_cast<const u32x4*>(&Bs[(wn + i * 16 + l15) * 40 + lg * 8]));
    #pragma unroll
    for (int mf = 0; mf < 4; ++mf)
      #pragma unroll
      for (int nf = 0; nf < 2; ++nf)
        acc[mf][nf] = mfma16(af[mf], bfr[nf], acc[mf][nf]);
    __syncthreads();
  }

  #pragma unroll
  for (int nf = 0; nf < 2; ++nf) {
    const int gc = n0 + wn + nf * 16 + l15;
    const float bv = bias[gc];
    #pragma unroll
    for (int mf = 0; mf < 4; ++mf) {
      #pragma unroll
      for (int r = 0; r < 4; ++r) {
        const int gr = m0 + wm + mf * 16 + lg * 4 + r;
        float v = (acc[mf][nf][r] + bv) * scale;
        if (mode == 0) {
          ((unsigned short*)Cp)[(((long)bz * H_ + (gc >> 6)) * S_ + gr) * DK_ + (gc & 63)] = f2bf(v);
        } else if (mode == 1) {
          ((unsigned short*)Cp)[(((long)bz * H_ + (gc >> 6)) * DK_ + (gc & 63)) * S_ + gr] = f2bf(v);
        } else {
          ((float*)Cp)[(long)gr * (B_ * D_) + (long)bz * D_ + gc] = v;
        }
      }
    }
  }
}

// fat projection launch: 3 independent GEMMs in one dispatch (grid 1536)
struct ProjArgs {
  const float* X[3];
  const float* W[3];
  const float* bias[3];
  void* out[3];
  float scale[3];
  int mode[3];
};

__global__ __launch_bounds__(256) void k_proj3(ProjArgs pa) {
  const int which = blockIdx.x >> 9;
  const int inner = blockIdx.x & 511;
  gemm_body<1, 0>(inner, pa.mode[which], pa.X[which], nullptr, 4096, 1024L,
                  pa.W[which], pa.bias[which], pa.out[which], pa.scale[which]);
}

// O-projection: A = sum of two bf16 partial slabs; B = Wo fp32 (converted in staging)
__global__ __launch_bounds__(256) void k_gemm_o(
    const unsigned short* __restrict__ Ap, const unsigned short* __restrict__ Ap2,
    const float* __restrict__ Bp, const float* __restrict__ bias,
    float* __restrict__ Cp) {
  gemm_body<0, 1>(blockIdx.x, 2, Ap, Ap2, 1024, 1048576L, Bp, bias, Cp, 1.0f);
}

// ---------------- softmax stats: m, 1/l per (b,h,q). Barrier-free streaming.
// grid 512 x 256 thr = 2048 waves (8 waves/CU); wave = (bh, 32 q-rows).
__global__ __launch_bounds__(256, 4) void k_stats(
    const unsigned short* __restrict__ qh,
    const unsigned short* __restrict__ kh,
    float2* __restrict__ mlout)
{
  const int tid = threadIdx.x;
  const int lane = tid & 63;
  const int w = tid >> 6;
  const int l15 = lane & 15;
  const int lg = lane >> 4;
  const int L = ((blockIdx.x & 7) << 6) | (blockIdx.x >> 3);  // XCD-chunked
  const int wtask = L * 4 + w;
  const int qq = wtask & 31;
  const int bh = wtask >> 5;
  const int q0 = qq * 32;

  bf16x8 qf[2][2];
  #pragma unroll
  for (int t = 0; t < 2; ++t) {
    const long qoff = ((long)bh * S_ + q0 + t * 16 + l15) * DK_ + lg * 8;
    qf[t][0] = ldg8(qh + qoff);
    qf[t][1] = ldg8(qh + qoff + 32);
  }
  const unsigned short* kbase = kh + (long)bh * S_ * DK_;

  float m[2], l[2];
  #pragma unroll
  for (int t = 0; t < 2; ++t) { m[t] = -3.0e38f; l[t] = 0.0f; }

  for (int kt = 0; kt < 16; ++kt) {
    bf16x8 kf[4][2];
    #pragma unroll
    for (int nf = 0; nf < 4; ++nf) {
      const unsigned short* kp = kbase + (long)(kt * 64 + nf * 16 + l15) * DK_ + lg * 8;
      kf[nf][0] = ldg8(kp);
      kf[nf][1] = ldg8(kp + 32);
    }
    #pragma unroll
    for (int t = 0; t < 2; ++t) {
      f32x4 sa[4] = {};
      #pragma unroll
      for (int nf = 0; nf < 4; ++nf) {
        sa[nf] = mfma16(kf[nf][0], qf[t][0], sa[nf]);   // swapped: lane owns q = l15
        sa[nf] = mfma16(kf[nf][1], qf[t][1], sa[nf]);
      }
      float tm = -3.0e38f;
      #pragma unroll
      for (int nf = 0; nf < 4; ++nf)
        #pragma unroll
        for (int r = 0; r < 4; ++r) tm = fmaxf(tm, sa[nf][r]);
      tm = fmaxf(tm, __shfl_xor(tm, 16));
      tm = fmaxf(tm, __shfl_xor(tm, 32));
      const float mn = fmaxf(m[t], tm);
      float ps = 0.0f;
      #pragma unroll
      for (int nf = 0; nf < 4; ++nf)
        #pragma unroll
        for (int r = 0; r < 4; ++r) ps += __expf(sa[nf][r] - mn);
      ps += __shfl_xor(ps, 16);
      ps += __shfl_xor(ps, 32);
      l[t] = l[t] * __expf(m[t] - mn) + ps;
      m[t] = mn;
    }
  }
  if (lane < 16) {
    #pragma unroll
    for (int t = 0; t < 2; ++t)
      mlout[(long)bh * S_ + q0 + t * 16 + l15] = make_float2(m[t], 1.0f / l[t]);
  }
}

// ---------------- fused pass2 (R14 measured-best, verbatim): p stored in a2-convention
// layout [plane h][q16][kc64] (XOR-swizzled); QK p-write = 4x ds_write_b64; mix read
// contiguous-u16; 1024 thr = 16 waves; 2 blk/CU; 3 barriers/kt; plain dim3 grid.
__global__ __launch_bounds__(1024, 8) void k_attn2(
    const unsigned short* __restrict__ qh,
    const unsigned short* __restrict__ kh,
    const unsigned short* __restrict__ vT,
    const float2* __restrict__ mlin,
    const float* __restrict__ head_att,
    const float* __restrict__ ln_g,
    const float* __restrict__ ln_b,
    unsigned short* __restrict__ Ym0,
    float* __restrict__ att_out)
{
  __shared__ unsigned short pS[16 * 1024];   // p bf16, plane h: [q16][kc64], XOR-swizzled
  __shared__ unsigned short a2[16 * 1024];   // attn2 bf16, plane g: [q16][kc64], XOR-swizzled
  __shared__ float haS[256];
  __shared__ float lngS[16];
  __shared__ float lnbS[16];
  const int tid = threadIdx.x;
  const int lane = tid & 63;
  const int w = tid >> 6;        // head in QK/PV phases; q-row in mix phase
  const int l15 = lane & 15;
  const int lg = lane >> 4;
  const int b = blockIdx.z;
  const int half = blockIdx.y;
  const int q0 = blockIdx.x * 16;
  const int kt0 = half * 8;

  if (tid < 256) haS[tid] = head_att[tid];
  if (tid < 16) { lngS[tid] = ln_g[tid]; lnbS[tid] = ln_b[tid]; }

  const int bh = b * H_ + w;
  const long qoff = ((long)bh * S_ + q0 + l15) * DK_ + lg * 8;
  bf16x8 qf0 = ldg8(qh + qoff);
  bf16x8 qf1 = ldg8(qh + qoff + 32);
  const unsigned short* kbase = kh + (long)bh * S_ * DK_;
  const unsigned short* vbase = vT + (long)bh * DK_ * S_;
  const float2 mml = mlin[(long)bh * S_ + q0 + l15];  // lane's q = l15

  unsigned short* Ym = Ym0 + (long)half * (B_ * S_ * D_);
  char* pSc = reinterpret_cast<char*>(pS);
  char* a2c = reinterpret_cast<char*>(a2);
  f32x4 yacc[4] = {};

  for (int kt = kt0; kt < kt0 + 8; ++kt) {
    // QK^T (swapped): lane holds 16 scores at q=l15, kc = nf*16+lg*4+r
    f32x4 sa[4] = {};
    #pragma unroll
    for (int nf = 0; nf < 4; ++nf) {
      const unsigned short* kp = kbase + (long)(kt * 64 + nf * 16 + l15) * DK_ + lg * 8;
      sa[nf] = mfma16(ldg8(kp), qf0, sa[nf]);
      sa[nf] = mfma16(ldg8(kp + 32), qf1, sa[nf]);
    }
    // p-write: 4 consecutive kc per nf -> one ds_write_b64 each (plane w, q=l15)
    #pragma unroll
    for (int nf = 0; nf < 4; ++nf) {
      const unsigned e0 = f2bf(__expf(sa[nf][0] - mml.x) * mml.y);
      const unsigned e1 = f2bf(__expf(sa[nf][1] - mml.x) * mml.y);
      const unsigned e2 = f2bf(__expf(sa[nf][2] - mml.x) * mml.y);
      const unsigned e3 = f2bf(__expf(sa[nf][3] - mml.x) * mml.y);
      const unsigned long long pk =
          (unsigned long long)(e0 | (e1 << 16)) |
          ((unsigned long long)(e2 | (e3 << 16)) << 32);
      unsigned bo = (unsigned)(w * 2048 + l15 * 128 + (nf * 16 + lg * 4) * 2);
      bo ^= (unsigned)((l15 & 7) << 4);
      *reinterpret_cast<unsigned long long*>(pSc + bo) = pk;
    }
    __syncthreads();   // B1: p ready

    // mix + LN; thread owns (q = w, kc = lane); contiguous-u16 read per plane
    const unsigned mixoff = (unsigned)((w * 128 + lane * 2) ^ ((w & 7) << 4));
    float mx[16];
    #pragma unroll
    for (int g = 0; g < 16; ++g) mx[g] = 0.0f;
    #pragma unroll
    for (int h = 0; h < 16; ++h) {
      const float p = bf2f(*reinterpret_cast<const unsigned short*>(pSc + h * 2048 + mixoff));
      #pragma unroll
      for (int g4 = 0; g4 < 4; ++g4) {
        const float4 hv = reinterpret_cast<const float4*>(&haS[h * 16])[g4];
        mx[g4 * 4 + 0] += p * hv.x;
        mx[g4 * 4 + 1] += p * hv.y;
        mx[g4 * 4 + 2] += p * hv.z;
        mx[g4 * 4 + 3] += p * hv.w;
      }
    }
    float mean = 0.0f;
    #pragma unroll
    for (int g = 0; g < 16; ++g) mean += mx[g];
    mean *= 0.0625f;
    float var = 0.0f;
    #pragma unroll
    for (int g = 0; g < 16; ++g) { const float dd = mx[g] - mean; var += dd * dd; }
    var *= 0.0625f;
    const float rs = rsqrtf(var + 1e-5f);

    float am = 0.0f;
    #pragma unroll
    for (int g = 0; g < 16; ++g) {
      const float o = (mx[g] - mean) * rs * lngS[g] + lnbS[g];
      am += o;
      *reinterpret_cast<unsigned short*>(a2c + g * 2048 + mixoff) = f2bf(o);
    }
    att_out[(long)b * S_ * S_ + (long)(q0 + w) * S_ + kt * 64 + lane] = am * 0.0625f;
    __syncthreads();   // B2: attn2 ready (also: all pS reads done)

    // PV: A = attn2 plane w (swizzled b128 read), B = vT rows (global)
    bf16x8 pa0, pa1;
    {
      const unsigned ub = (unsigned)(w * 2048 + l15 * 128 + lg * 16);
      const unsigned swz = (unsigned)((l15 & 7) << 4);
      pa0 = __builtin_bit_cast(bf16x8, *reinterpret_cast<const u32x4*>(a2c + (ub ^ swz)));
      pa1 = __builtin_bit_cast(bf16x8, *reinterpret_cast<const u32x4*>(a2c + ((ub + 64) ^ swz)));
    }
    #pragma unroll
    for (int nf = 0; nf < 4; ++nf) {
      const unsigned short* vp = vbase + (long)(nf * 16 + l15) * S_ + kt * 64 + lg * 8;
      yacc[nf] = mfma16(pa0, ldg8(vp), yacc[nf]);
      yacc[nf] = mfma16(pa1, ldg8(vp + 32), yacc[nf]);
    }
    __syncthreads();   // B3: PV reads done; keeps all waves in the same kt-window
  }

  // epilogue: partial merged-head Y (bf16) [B,S,D] for this kc-half
  #pragma unroll
  for (int nf = 0; nf < 4; ++nf)
    #pragma unroll
    for (int r = 0; r < 4; ++r)
      Ym[((long)b * S_ + q0 + lg * 4 + r) * D_ + w * 64 + nf * 16 + l15] = f2bf(yacc[nf][r]);
}

extern "C" void kernel_launch(void* const* d_in, const int* in_sizes, int n_in,
                              void* d_out, int out_size, void* d_ws, size_t ws_size,
                              hipStream_t stream) {
  const float* q_in = (const float*)d_in[0];
  const float* k_in = (const float*)d_in[1];
  const float* v_in = (const float*)d_in[2];
  const float* Wq = (const float*)d_in[3];
  const float* bq = (const float*)d_in[4];
  const float* Wk = (const float*)d_in[5];
  const float* bk = (const float*)d_in[6];
  const float* Wv = (const float*)d_in[7];
  const float* bv = (const float*)d_in[8];
  const float* Wo = (const float*)d_in[9];
  const float* bo = (const float*)d_in[10];
  const float* head_att = (const float*)d_in[11];
  const float* ln_g = (const float*)d_in[12];
  const float* ln_b = (const float*)d_in[13];

  char* ws = (char*)d_ws;
  const long MB = 1048576L;
  unsigned short* qhp = (unsigned short*)(ws + 8 * MB);
  unsigned short* khp = (unsigned short*)(ws + 16 * MB);
  unsigned short* vTp = (unsigned short*)(ws + 24 * MB);
  unsigned short* Ymb = (unsigned short*)(ws + 32 * MB);   // 2 x 8 MB bf16 partials
  float2* mlb = (float2*)(ws + 48 * MB);                   // 512 KB

  // fat launch: q (pre-scaled by 1/8), k, v projections in one dispatch
  // (weight fp32->bf16 conversion fused into B staging; k_convert removed)
  ProjArgs pa;
  pa.X[0] = q_in; pa.W[0] = Wq; pa.bias[0] = bq; pa.out[0] = qhp; pa.scale[0] = 0.125f; pa.mode[0] = 0;
  pa.X[1] = k_in; pa.W[1] = Wk; pa.bias[1] = bk; pa.out[1] = khp; pa.scale[1] = 1.0f;   pa.mode[1] = 0;
  pa.X[2] = v_in; pa.W[2] = Wv; pa.bias[2] = bv; pa.out[2] = vTp; pa.scale[2] = 1.0f;   pa.mode[2] = 1;
  k_proj3<<<1536, 256, 0, stream>>>(pa);

  k_stats<<<512, 256, 0, stream>>>(qhp, khp, mlb);

  float* att_map = (float*)d_out + (long)S_ * B_ * D_;
  k_attn2<<<dim3(64, 2, 4), 1024, 0, stream>>>(qhp, khp, vTp, mlb, head_att, ln_g, ln_b,
                                               Ymb, att_map);

  k_gemm_o<<<512, 256, 0, stream>>>(Ymb, Ymb + (long)B_ * S_ * D_, Wo, bo, (float*)d_out);
}

// Round 17
// 285.569 us; speedup vs baseline: 8.2033x; 1.0071x over previous
//
#include <hip/hip_runtime.h>

#define D_ 1024
#define H_ 16
#define DK_ 64
#define S_ 1024
#define B_ 4

typedef __attribute__((ext_vector_type(4))) float f32x4;
typedef __attribute__((ext_vector_type(2))) float f32x2;
typedef __attribute__((ext_vector_type(8))) short bf16x8;
typedef __attribute__((ext_vector_type(4))) unsigned int u32x4;

__device__ __forceinline__ unsigned short f2bf(float f) {
  unsigned u = __builtin_bit_cast(unsigned, f);
  u += 0x7FFFu + ((u >> 16) & 1u);
  return (unsigned short)(u >> 16);
}

__device__ __forceinline__ float bf2f(unsigned short s) {
  return __builtin_bit_cast(float, (unsigned)s << 16);
}

__device__ __forceinline__ bf16x8 ldg8(const unsigned short* p) {
  return __builtin_bit_cast(bf16x8, *reinterpret_cast<const u32x4*>(p));
}

__device__ __forceinline__ f32x4 mfma16(bf16x8 a, bf16x8 b, f32x4 c) {
  return __builtin_amdgcn_mfma_f32_16x16x32_bf16(a, b, c, 0, 0, 0);
}

// ---------------- generic NT GEMM body: C[m,n] = (sum_k A[m,k]*B[n,k] + bias[n])*scale
// M=N=K=1024, BM=128 BN=64 BK=32. bid in [0,512), XCD-chunked (bz|m|n).
// B operand is fp32 (weights), converted to bf16 during LDS staging (conversion fused).
// mode 0: ->qh/kh bf16 [B,H,S,DK]; mode 1: ->vT bf16 [B,H,DK,S]; mode 2: -> d_out fp32.
// AF32: A fp32 (converted in staging). SUM2: A = Ap+Ap2 (bf16 partials).
template <int AF32, int SUM2>
__device__ __forceinline__ void gemm_body(
    int bid, int mode,
    const void* __restrict__ Ap, const void* __restrict__ Ap2, int lda, long azs,
    const float* __restrict__ Bp,
    const float* __restrict__ bias,
    void* __restrict__ Cp, float scale)
{
  __shared__ unsigned short As[128 * 40];
  __shared__ unsigned short Bs[64 * 40];
  const int tid = threadIdx.x;
  const int lane = tid & 63;
  const int w = tid >> 6;
  const int wm = (w >> 1) * 64;      // 2 wave-rows of 64
  const int wn = (w & 1) * 32;       // 2 wave-cols of 32
  const int L = ((bid & 7) << 6) | (bid >> 3);   // XCD-chunked, bijective
  const int n0 = (L & 15) * 64;
  const int m0 = ((L >> 4) & 7) * 128;
  const int bz = L >> 7;
  const int srow = tid >> 1;         // A staging: 128 rows, 2 halves
  const int shalf = tid & 1;
  const int brow = tid >> 2;         // B staging: 64 rows, 4 chunks of 8
  const int bq = tid & 3;
  const int l15 = lane & 15;
  const int lg = lane >> 4;

  f32x4 acc[4][2] = {};

  for (int kt = 0; kt < 32; ++kt) {
    const long aoff = (long)bz * azs + (long)(m0 + srow) * lda + kt * 32 + shalf * 16;
    if (AF32) {
      const float4* g4 = reinterpret_cast<const float4*>((const float*)Ap + aoff);
      unsigned* dst = reinterpret_cast<unsigned*>(&As[srow * 40 + shalf * 16]);
      #pragma unroll
      for (int i = 0; i < 4; ++i) {
        float4 v = g4[i];
        dst[2 * i]     = (unsigned)f2bf(v.x) | ((unsigned)f2bf(v.y) << 16);
        dst[2 * i + 1] = (unsigned)f2bf(v.z) | ((unsigned)f2bf(v.w) << 16);
      }
    } else if (SUM2) {
      const unsigned short* ga = (const unsigned short*)Ap + aoff;
      const unsigned short* ga2 = (const unsigned short*)Ap2 + aoff;
      u32x4 va[2] = { *reinterpret_cast<const u32x4*>(ga), *reinterpret_cast<const u32x4*>(ga + 8) };
      u32x4 vb[2] = { *reinterpret_cast<const u32x4*>(ga2), *reinterpret_cast<const u32x4*>(ga2 + 8) };
      unsigned* dst = reinterpret_cast<unsigned*>(&As[srow * 40 + shalf * 16]);
      #pragma unroll
      for (int p = 0; p < 2; ++p)
        #pragma unroll
        for (int i = 0; i < 4; ++i) {
          const unsigned x = va[p][i], y = vb[p][i];
          const float lo = __builtin_bit_cast(float, x << 16) + __builtin_bit_cast(float, y << 16);
          const float hi = __builtin_bit_cast(float, x & 0xffff0000u) + __builtin_bit_cast(float, y & 0xffff0000u);
          dst[p * 4 + i] = (unsigned)f2bf(lo) | ((unsigned)f2bf(hi) << 16);
        }
    } else {
      const unsigned short* ga = (const unsigned short*)Ap + aoff;
      u32x4 av0 = *reinterpret_cast<const u32x4*>(ga);
      u32x4 av1 = *reinterpret_cast<const u32x4*>(ga + 8);
      *reinterpret_cast<u32x4*>(&As[srow * 40 + shalf * 16]) = av0;
      *reinterpret_cast<u32x4*>(&As[srow * 40 + shalf * 16 + 8]) = av1;
    }
    {
      // B staging: fp32 weights -> bf16 (conversion fused)
      const float4* gb = reinterpret_cast<const float4*>(Bp + (long)(n0 + brow) * 1024 + kt * 32 + bq * 8);
      float4 v0 = gb[0];
      float4 v1 = gb[1];
      unsigned* dst = reinterpret_cast<unsigned*>(&Bs[brow * 40 + bq * 8]);
      dst[0] = (unsigned)f2bf(v0.x) | ((unsigned)f2bf(v0.y) << 16);
      dst[1] = (unsigned)f2bf(v0.z) | ((unsigned)f2bf(v0.w) << 16);
      dst[2] = (unsigned)f2bf(v1.x) | ((unsigned)f2bf(v1.y) << 16);
      dst[3] = (unsigned)f2bf(v1.z) | ((unsigned)f2bf(v1.w) << 16);
    }
    __syncthreads();
    bf16x8 af[4], bfr[2];
    #pragma unroll
    for (int i = 0; i < 4; ++i)
      af[i] = __builtin_bit_cast(bf16x8, *reinterpret_cast<const u32x4*>(&As[(wm + i * 16 + l15) * 40 + lg * 8]));
    #pragma unroll
    for (int i = 0; i < 2; ++i)
      bfr[i] = __builtin_bit_cast(bf16x8, *reinterpret_cast<const u32x4*>(&Bs[(wn + i * 16 + l15) * 40 + lg * 8]));
    #pragma unroll
    for (int mf = 0; mf < 4; ++mf)
      #pragma unroll
      for (int nf = 0; nf < 2; ++nf)
        acc[mf][nf] = mfma16(af[mf], bfr[nf], acc[mf][nf]);
    __syncthreads();
  }

  #pragma unroll
  for (int nf = 0; nf < 2; ++nf) {
    const int gc = n0 + wn + nf * 16 + l15;
    const float bv = bias[gc];
    #pragma unroll
    for (int mf = 0; mf < 4; ++mf) {
      #pragma unroll
      for (int r = 0; r < 4; ++r) {
        const int gr = m0 + wm + mf * 16 + lg * 4 + r;
        float v = (acc[mf][nf][r] + bv) * scale;
        if (mode == 0) {
          ((unsigned short*)Cp)[(((long)bz * H_ + (gc >> 6)) * S_ + gr) * DK_ + (gc & 63)] = f2bf(v);
        } else if (mode == 1) {
          ((unsigned short*)Cp)[(((long)bz * H_ + (gc >> 6)) * DK_ + (gc & 63)) * S_ + gr] = f2bf(v);
        } else {
          ((float*)Cp)[(long)gr * (B_ * D_) + (long)bz * D_ + gc] = v;
        }
      }
    }
  }
}

// fat projection launch: 3 independent GEMMs in one dispatch (grid 1536)
struct ProjArgs {
  const float* X[3];
  const float* W[3];
  const float* bias[3];
  void* out[3];
  float scale[3];
  int mode[3];
};

__global__ __launch_bounds__(256) void k_proj3(ProjArgs pa) {
  const int which = blockIdx.x >> 9;
  const int inner = blockIdx.x & 511;
  gemm_body<1, 0>(inner, pa.mode[which], pa.X[which], nullptr, 4096, 1024L,
                  pa.W[which], pa.bias[which], pa.out[which], pa.scale[which]);
}

// O-projection: A = sum of two bf16 partial slabs; B = Wo fp32 (converted in staging)
__global__ __launch_bounds__(256) void k_gemm_o(
    const unsigned short* __restrict__ Ap, const unsigned short* __restrict__ Ap2,
    const float* __restrict__ Bp, const float* __restrict__ bias,
    float* __restrict__ Cp) {
  gemm_body<0, 1>(blockIdx.x, 2, Ap, Ap2, 1024, 1048576L, Bp, bias, Cp, 1.0f);
}

// ---------------- softmax stats: m, 1/l per (b,h,q). Barrier-free streaming.
// grid 512 x 256 thr = 2048 waves (8 waves/CU); wave = (bh, 32 q-rows).
__global__ __launch_bounds__(256, 4) void k_stats(
    const unsigned short* __restrict__ qh,
    const unsigned short* __restrict__ kh,
    float2* __restrict__ mlout)
{
  const int tid = threadIdx.x;
  const int lane = tid & 63;
  const int w = tid >> 6;
  const int l15 = lane & 15;
  const int lg = lane >> 4;
  const int L = ((blockIdx.x & 7) << 6) | (blockIdx.x >> 3);  // XCD-chunked
  const int wtask = L * 4 + w;
  const int qq = wtask & 31;
  const int bh = wtask >> 5;
  const int q0 = qq * 32;

  bf16x8 qf[2][2];
  #pragma unroll
  for (int t = 0; t < 2; ++t) {
    const long qoff = ((long)bh * S_ + q0 + t * 16 + l15) * DK_ + lg * 8;
    qf[t][0] = ldg8(qh + qoff);
    qf[t][1] = ldg8(qh + qoff + 32);
  }
  const unsigned short* kbase = kh + (long)bh * S_ * DK_;

  float m[2], l[2];
  #pragma unroll
  for (int t = 0; t < 2; ++t) { m[t] = -3.0e38f; l[t] = 0.0f; }

  for (int kt = 0; kt < 16; ++kt) {
    bf16x8 kf[4][2];
    #pragma unroll
    for (int nf = 0; nf < 4; ++nf) {
      const unsigned short* kp = kbase + (long)(kt * 64 + nf * 16 + l15) * DK_ + lg * 8;
      kf[nf][0] = ldg8(kp);
      kf[nf][1] = ldg8(kp + 32);
    }
    #pragma unroll
    for (int t = 0; t < 2; ++t) {
      f32x4 sa[4] = {};
      #pragma unroll
      for (int nf = 0; nf < 4; ++nf) {
        sa[nf] = mfma16(kf[nf][0], qf[t][0], sa[nf]);   // swapped: lane owns q = l15
        sa[nf] = mfma16(kf[nf][1], qf[t][1], sa[nf]);
      }
      float tm = -3.0e38f;
      #pragma unroll
      for (int nf = 0; nf < 4; ++nf)
        #pragma unroll
        for (int r = 0; r < 4; ++r) tm = fmaxf(tm, sa[nf][r]);
      tm = fmaxf(tm, __shfl_xor(tm, 16));
      tm = fmaxf(tm, __shfl_xor(tm, 32));
      const float mn = fmaxf(m[t], tm);
      float ps = 0.0f;
      #pragma unroll
      for (int nf = 0; nf < 4; ++nf)
        #pragma unroll
        for (int r = 0; r < 4; ++r) ps += __expf(sa[nf][r] - mn);
      ps += __shfl_xor(ps, 16);
      ps += __shfl_xor(ps, 32);
      l[t] = l[t] * __expf(m[t] - mn) + ps;
      m[t] = mn;
    }
  }
  if (lane < 16) {
    #pragma unroll
    for (int t = 0; t < 2; ++t)
      mlout[(long)bh * S_ + q0 + t * 16 + l15] = make_float2(m[t], 1.0f / l[t]);
  }
}

// ---------------- fused pass2 (R14/R16 structure; ONLY change: mix accumulators are
// float2 ext-vectors so the 256-FMA mix emits v_pk_fma_f32 packed pairs, halving
// VALU instruction count; accumulation order over h preserved -> bitwise identical).
__global__ __launch_bounds__(1024, 8) void k_attn2(
    const unsigned short* __restrict__ qh,
    const unsigned short* __restrict__ kh,
    const unsigned short* __restrict__ vT,
    const float2* __restrict__ mlin,
    const float* __restrict__ head_att,
    const float* __restrict__ ln_g,
    const float* __restrict__ ln_b,
    unsigned short* __restrict__ Ym0,
    float* __restrict__ att_out)
{
  __shared__ unsigned short pS[16 * 1024];   // p bf16, plane h: [q16][kc64], XOR-swizzled
  __shared__ unsigned short a2[16 * 1024];   // attn2 bf16, plane g: [q16][kc64], XOR-swizzled
  __shared__ float haS[256];
  __shared__ float lngS[16];
  __shared__ float lnbS[16];
  const int tid = threadIdx.x;
  const int lane = tid & 63;
  const int w = tid >> 6;        // head in QK/PV phases; q-row in mix phase
  const int l15 = lane & 15;
  const int lg = lane >> 4;
  const int b = blockIdx.z;
  const int half = blockIdx.y;
  const int q0 = blockIdx.x * 16;
  const int kt0 = half * 8;

  if (tid < 256) haS[tid] = head_att[tid];
  if (tid < 16) { lngS[tid] = ln_g[tid]; lnbS[tid] = ln_b[tid]; }

  const int bh = b * H_ + w;
  const long qoff = ((long)bh * S_ + q0 + l15) * DK_ + lg * 8;
  bf16x8 qf0 = ldg8(qh + qoff);
  bf16x8 qf1 = ldg8(qh + qoff + 32);
  const unsigned short* kbase = kh + (long)bh * S_ * DK_;
  const unsigned short* vbase = vT + (long)bh * DK_ * S_;
  const float2 mml = mlin[(long)bh * S_ + q0 + l15];  // lane's q = l15

  unsigned short* Ym = Ym0 + (long)half * (B_ * S_ * D_);
  char* pSc = reinterpret_cast<char*>(pS);
  char* a2c = reinterpret_cast<char*>(a2);
  f32x4 yacc[4] = {};

  for (int kt = kt0; kt < kt0 + 8; ++kt) {
    // QK^T (swapped): lane holds 16 scores at q=l15, kc = nf*16+lg*4+r
    f32x4 sa[4] = {};
    #pragma unroll
    for (int nf = 0; nf < 4; ++nf) {
      const unsigned short* kp = kbase + (long)(kt * 64 + nf * 16 + l15) * DK_ + lg * 8;
      sa[nf] = mfma16(ldg8(kp), qf0, sa[nf]);
      sa[nf] = mfma16(ldg8(kp + 32), qf1, sa[nf]);
    }
    // p-write: 4 consecutive kc per nf -> one ds_write_b64 each (plane w, q=l15)
    #pragma unroll
    for (int nf = 0; nf < 4; ++nf) {
      const unsigned e0 = f2bf(__expf(sa[nf][0] - mml.x) * mml.y);
      const unsigned e1 = f2bf(__expf(sa[nf][1] - mml.x) * mml.y);
      const unsigned e2 = f2bf(__expf(sa[nf][2] - mml.x) * mml.y);
      const unsigned e3 = f2bf(__expf(sa[nf][3] - mml.x) * mml.y);
      const unsigned long long pk =
          (unsigned long long)(e0 | (e1 << 16)) |
          ((unsigned long long)(e2 | (e3 << 16)) << 32);
      unsigned bo = (unsigned)(w * 2048 + l15 * 128 + (nf * 16 + lg * 4) * 2);
      bo ^= (unsigned)((l15 & 7) << 4);
      *reinterpret_cast<unsigned long long*>(pSc + bo) = pk;
    }
    __syncthreads();   // B1: p ready

    // mix + LN; thread owns (q = w, kc = lane); packed f32x2 accumulation (v_pk_fma_f32)
    const unsigned mixoff = (unsigned)((w * 128 + lane * 2) ^ ((w & 7) << 4));
    f32x2 mx2[8];
    #pragma unroll
    for (int g2 = 0; g2 < 8; ++g2) mx2[g2] = f32x2{0.0f, 0.0f};
    #pragma unroll
    for (int h = 0; h < 16; ++h) {
      const float p = bf2f(*reinterpret_cast<const unsigned short*>(pSc + h * 2048 + mixoff));
      const f32x2 pp = {p, p};
      const f32x2* hv2 = reinterpret_cast<const f32x2*>(&haS[h * 16]);
      #pragma unroll
      for (int g2 = 0; g2 < 8; ++g2)
        mx2[g2] += pp * hv2[g2];
    }
    f32x2 s12 = {0.0f, 0.0f};
    #pragma unroll
    for (int g2 = 0; g2 < 8; ++g2) s12 += mx2[g2];
    const float mean = (s12[0] + s12[1]) * 0.0625f;
    f32x2 v2 = {0.0f, 0.0f};
    const f32x2 mm = {mean, mean};
    #pragma unroll
    for (int g2 = 0; g2 < 8; ++g2) {
      const f32x2 dd = mx2[g2] - mm;
      v2 += dd * dd;
    }
    const float var = (v2[0] + v2[1]) * 0.0625f;
    const float rs = rsqrtf(var + 1e-5f);

    float am = 0.0f;
    #pragma unroll
    for (int g = 0; g < 16; ++g) {
      const float o = (mx2[g >> 1][g & 1] - mean) * rs * lngS[g] + lnbS[g];
      am += o;
      *reinterpret_cast<unsigned short*>(a2c + g * 2048 + mixoff) = f2bf(o);
    }
    att_out[(long)b * S_ * S_ + (long)(q0 + w) * S_ + kt * 64 + lane] = am * 0.0625f;
    __syncthreads();   // B2: attn2 ready (also: all pS reads done)

    // PV: A = attn2 plane w (swizzled b128 read), B = vT rows (global)
    bf16x8 pa0, pa1;
    {
      const unsigned ub = (unsigned)(w * 2048 + l15 * 128 + lg * 16);
      const unsigned swz = (unsigned)((l15 & 7) << 4);
      pa0 = __builtin_bit_cast(bf16x8, *reinterpret_cast<const u32x4*>(a2c + (ub ^ swz)));
      pa1 = __builtin_bit_cast(bf16x8, *reinterpret_cast<const u32x4*>(a2c + ((ub + 64) ^ swz)));
    }
    #pragma unroll
    for (int nf = 0; nf < 4; ++nf) {
      const unsigned short* vp = vbase + (long)(nf * 16 + l15) * S_ + kt * 64 + lg * 8;
      yacc[nf] = mfma16(pa0, ldg8(vp), yacc[nf]);
      yacc[nf] = mfma16(pa1, ldg8(vp + 32), yacc[nf]);
    }
    __syncthreads();   // B3: PV reads done; keeps all waves in the same kt-window
  }

  // epilogue: partial merged-head Y (bf16) [B,S,D] for this kc-half
  #pragma unroll
  for (int nf = 0; nf < 4; ++nf)
    #pragma unroll
    for (int r = 0; r < 4; ++r)
      Ym[((long)b * S_ + q0 + lg * 4 + r) * D_ + w * 64 + nf * 16 + l15] = f2bf(yacc[nf][r]);
}

extern "C" void kernel_launch(void* const* d_in, const int* in_sizes, int n_in,
                              void* d_out, int out_size, void* d_ws, size_t ws_size,
                              hipStream_t stream) {
  const float* q_in = (const float*)d_in[0];
  const float* k_in = (const float*)d_in[1];
  const float* v_in = (const float*)d_in[2];
  const float* Wq = (const float*)d_in[3];
  const float* bq = (const float*)d_in[4];
  const float* Wk = (const float*)d_in[5];
  const float* bk = (const float*)d_in[6];
  const float* Wv = (const float*)d_in[7];
  const float* bv = (const float*)d_in[8];
  const float* Wo = (const float*)d_in[9];
  const float* bo = (const float*)d_in[10];
  const float* head_att = (const float*)d_in[11];
  const float* ln_g = (const float*)d_in[12];
  const float* ln_b = (const float*)d_in[13];

  char* ws = (char*)d_ws;
  const long MB = 1048576L;
  unsigned short* qhp = (unsigned short*)(ws + 8 * MB);
  unsigned short* khp = (unsigned short*)(ws + 16 * MB);
  unsigned short* vTp = (unsigned short*)(ws + 24 * MB);
  unsigned short* Ymb = (unsigned short*)(ws + 32 * MB);   // 2 x 8 MB bf16 partials
  float2* mlb = (float2*)(ws + 48 * MB);                   // 512 KB

  // fat launch: q (pre-scaled by 1/8), k, v projections in one dispatch
  ProjArgs pa;
  pa.X[0] = q_in; pa.W[0] = Wq; pa.bias[0] = bq; pa.out[0] = qhp; pa.scale[0] = 0.125f; pa.mode[0] = 0;
  pa.X[1] = k_in; pa.W[1] = Wk; pa.bias[1] = bk; pa.out[1] = khp; pa.scale[1] = 1.0f;   pa.mode[1] = 0;
  pa.X[2] = v_in; pa.W[2] = Wv; pa.bias[2] = bv; pa.out[2] = vTp; pa.scale[2] = 1.0f;   pa.mode[2] = 1;
  k_proj3<<<1536, 256, 0, stream>>>(pa);

  k_stats<<<512, 256, 0, stream>>>(qhp, khp, mlb);

  float* att_map = (float*)d_out + (long)S_ * B_ * D_;
  k_attn2<<<dim3(64, 2, 4), 1024, 0, stream>>>(qhp, khp, vTp, mlb, head_att, ln_g, ln_b,
                                               Ymb, att_map);

  k_gemm_o<<<512, 256, 0, stream>>>(Ymb, Ymb + (long)B_ * S_ * D_, Wo, bo, (float*)d_out);
}